// Round 1
// baseline (1447.127 us; speedup 1.0000x reference)
//
#include <hip/hip_runtime.h>

// 2D acoustic FDTD, temporally blocked: K=8 steps per launch, halo-K strips.
// Strips are full-width (no column halo); one block per (strip, batch).
// LDS holds ping-pong u1 arrays only; u2 and c2 live in per-thread registers.

#define HH 256
#define WW 256
#define KT 8                 // time steps per kernel launch (halo width)
#define SHR 32               // strip interior height
#define NSTRIP (HH / SHR)    // 8 strips
#define RLMAX (SHR + 2 * KT) // 48 max region rows
#define NTH 1024
#define C2SCALE 1.0e-4f      // DT / DX

__global__ __launch_bounds__(NTH) void wave_chunk(
    const float* __restrict__ x, const float* __restrict__ vp,
    const int* __restrict__ src_y, const int* __restrict__ src_x,
    const int* __restrict__ rec_y, const int* __restrict__ rec_x,
    float* __restrict__ gcur, float* __restrict__ gprev,
    float* __restrict__ out, int t0, int nsteps, int B, int NR)
{
    __shared__ float lds[2][RLMAX][WW];   // 96 KB: ping-pong u1 field

    const int strip = blockIdx.x;
    const int bb    = blockIdx.y;
    const int y0    = strip * SHR;
    const int lo    = max(0, y0 - KT);
    const int hi    = min(HH, y0 + SHR + KT);
    const int RL    = hi - lo;            // region rows (40 or 48)

    const int tid  = threadIdx.x;
    const int lane = tid & 63;            // wave spans one full row
    const int xg   = lane * 4;            // this thread's 4-col group
    const int rs   = tid >> 6;            // row slot 0..15

    float4 pv[3];                         // u_{t-1} for my cells (register-resident)
    float4 c2[3];                         // (vp*DT/DX)^2 for my cells

    const size_t bbase = (size_t)bb * HH * WW;

    // ---- load region: u1 -> LDS, u2 -> regs, c2 -> regs ----
    #pragma unroll
    for (int j = 0; j < 3; ++j) {
        int r = rs + 16 * j;
        if (r < RL) {
            int gy = lo + r;
            size_t gi = bbase + (size_t)gy * WW + xg;
            *(float4*)&lds[0][r][xg] = *(const float4*)&gcur[gi];
            pv[j] = *(const float4*)&gprev[gi];
            float4 v = *(const float4*)&vp[gy * WW + xg];
            float4 cc;
            cc.x = v.x * C2SCALE; cc.y = v.y * C2SCALE;
            cc.z = v.z * C2SCALE; cc.w = v.w * C2SCALE;
            cc.x *= cc.x; cc.y *= cc.y; cc.z *= cc.z; cc.w *= cc.w;
            c2[j] = cc;
        }
    }

    const int sy = src_y[bb];
    const int sx = src_x[bb];

    int ry = 0, rx = 0;
    bool ract = false;
    if (tid < NR) {
        ry = rec_y[tid];
        rx = rec_x[tid];
        ract = (ry >= y0) && (ry < y0 + SHR);
    }
    __syncthreads();

    int cur = 0;
    for (int s = 0; s < nsteps; ++s) {
        const int t = t0 + s;
        const float xi = x[t * B + bb];

        #pragma unroll
        for (int j = 0; j < 3; ++j) {
            int r = rs + 16 * j;           // wave-uniform (whole wave same r)
            if (r < RL) {
                float4 c = *(const float4*)&lds[cur][r][xg];
                float4 n  = make_float4(0.f, 0.f, 0.f, 0.f);
                float4 ss = make_float4(0.f, 0.f, 0.f, 0.f);
                if (r > 0)      n  = *(const float4*)&lds[cur][r - 1][xg];
                if (r < RL - 1) ss = *(const float4*)&lds[cur][r + 1][xg];
                // west/east via intra-wave shuffle (wave covers the full row)
                float wl = __shfl_up(c.w, 1);
                if (lane == 0)  wl = 0.0f;   // domain edge x=0
                float er = __shfl_down(c.x, 1);
                if (lane == 63) er = 0.0f;   // domain edge x=255

                float4 lap;
                lap.x = n.x + ss.x + wl  + c.y - 4.0f * c.x;
                lap.y = n.y + ss.y + c.x + c.z - 4.0f * c.y;
                lap.z = n.z + ss.z + c.y + c.w - 4.0f * c.z;
                lap.w = n.w + ss.w + c.z + er  - 4.0f * c.w;

                float4 un;
                un.x = 2.0f * c.x - pv[j].x + c2[j].x * lap.x;
                un.y = 2.0f * c.y - pv[j].y + c2[j].y * lap.y;
                un.z = 2.0f * c.z - pv[j].z + c2[j].z * lap.z;
                un.w = 2.0f * c.w - pv[j].w + c2[j].w * lap.w;

                int gy = lo + r;
                if (gy == sy && sx >= xg && sx < xg + 4) {
                    ((float*)&un)[sx - xg] += xi;   // source injection
                }
                pv[j] = c;                           // new u_{t-1} = old center
                *(float4*)&lds[cur ^ 1][r][xg] = un;
            }
        }
        __syncthreads();
        cur ^= 1;
        // receiver gather from just-computed field (interior rows always valid)
        if (ract) {
            out[((size_t)t * B + bb) * NR + tid] = lds[cur][ry - lo][rx];
        }
    }

    // ---- write back interior rows of both time levels ----
    #pragma unroll
    for (int j = 0; j < 3; ++j) {
        int r = rs + 16 * j;
        int gy = lo + r;
        if (r < RL && gy >= y0 && gy < y0 + SHR) {
            size_t gi = bbase + (size_t)gy * WW + xg;
            *(float4*)&gcur[gi]  = *(float4*)&lds[cur][r][xg];
            *(float4*)&gprev[gi] = pv[j];
        }
    }
}

extern "C" void kernel_launch(void* const* d_in, const int* in_sizes, int n_in,
                              void* d_out, int out_size, void* d_ws, size_t ws_size,
                              hipStream_t stream) {
    const float* x     = (const float*)d_in[0];
    const float* vp    = (const float*)d_in[1];
    const int* src_y   = (const int*)d_in[2];
    const int* src_x   = (const int*)d_in[3];
    const int* rec_y   = (const int*)d_in[4];
    const int* rec_x   = (const int*)d_in[5];

    const int B  = in_sizes[2];
    const int NR = in_sizes[4];
    const int NT = in_sizes[0] / B;

    float* gcur  = (float*)d_ws;
    float* gprev = gcur + (size_t)B * HH * WW;
    float* outp  = (float*)d_out;

    // zero the wavefield state (ws is poisoned before every call)
    hipMemsetAsync(d_ws, 0, (size_t)2 * B * HH * WW * sizeof(float), stream);

    dim3 grid(NSTRIP, B), block(NTH);
    for (int t0 = 0; t0 < NT; t0 += KT) {
        int ns = (NT - t0 < KT) ? (NT - t0) : KT;
        wave_chunk<<<grid, block, 0, stream>>>(x, vp, src_y, src_x, rec_y, rec_x,
                                               gcur, gprev, outp, t0, ns, B, NR);
    }
}